// Round 1
// baseline (206.097 us; speedup 1.0000x reference)
//
#include <hip/hip_runtime.h>
#include <math.h>

constexpr int B = 256, STEP = 32, DF = 256, DZ = 64;
#define LOG_2PI 1.837877066409345f
#define LOG_C   16.36495572888985f   // log(256 * 50000)

__device__ __forceinline__ float warpReduceSum64(float v) {
    for (int o = 32; o > 0; o >>= 1) v += __shfl_down(v, o, 64);
    return v;
}
__device__ __forceinline__ float warpReduceMax64(float v) {
    for (int o = 32; o > 0; o >>= 1) v = fmaxf(v, __shfl_down(v, o, 64));
    return v;
}

// 256-thread block reductions; lds must be float[4]; result valid in ALL threads.
__device__ __forceinline__ float blockReduceSum256(float v, float* lds) {
    int wid = threadIdx.x >> 6, lane = threadIdx.x & 63;
    v = warpReduceSum64(v);
    if (lane == 0) lds[wid] = v;
    __syncthreads();
    float r = lds[0] + lds[1] + lds[2] + lds[3];
    __syncthreads();
    return r;
}
__device__ __forceinline__ float blockReduceMax256(float v, float* lds) {
    int wid = threadIdx.x >> 6, lane = threadIdx.x & 63;
    v = warpReduceMax64(v);
    if (lane == 0) lds[wid] = v;
    __syncthreads();
    float r = fmaxf(fmaxf(lds[0], lds[1]), fmaxf(lds[2], lds[3]));
    __syncthreads();
    return r;
}

// Transpose z arrays [B,STEP,DZ] -> [STEP,B,DZ]; precompute e=exp(-lv), wc[s,j]=sum_d(2lv+log2pi).
// grid = B*STEP blocks (b = j*STEP + s), block = 64 threads (d).
__global__ void k_pre_z(const float* __restrict__ zm, const float* __restrict__ zl,
                        const float* __restrict__ zs,
                        float* __restrict__ zm_t, float* __restrict__ e_t,
                        float* __restrict__ zs_t, float* __restrict__ wc) {
    int b = blockIdx.x;
    int d = threadIdx.x;
    int j = b / STEP, s = b % STEP;
    int src = b * DZ + d;
    int dst = (s * B + j) * DZ + d;
    float lv = zl[src];
    zm_t[dst] = zm[src];
    e_t[dst]  = expf(-lv);
    zs_t[dst] = zs[src];
    float r = warpReduceSum64(2.0f * lv + LOG_2PI);
    if (d == 0) wc[s * B + j] = r;
}

// Precompute ef[j,d]=exp(-f_logvar), wcf[j]=sum_d(2lv+log2pi). grid=B, block=DF.
__global__ void k_pre_f(const float* __restrict__ fl,
                        float* __restrict__ ef, float* __restrict__ wcf) {
    __shared__ float lds[4];
    int j = blockIdx.x, d = threadIdx.x;
    float lv = fl[j * DF + d];
    ef[j * DF + d] = expf(-lv);
    float r = blockReduceSum256(2.0f * lv + LOG_2PI, lds);
    if (d == 0) wcf[j] = r;
}

// sum_f[i,j] + logsumexp over j -> hneg_f[i]. grid=B (i), block=B (j).
__global__ void k_f(const float* __restrict__ fm, const float* __restrict__ fs,
                    const float* __restrict__ ef, const float* __restrict__ wcf,
                    float* __restrict__ sum_f, float* __restrict__ hneg_f) {
    int i = blockIdx.x, j = threadIdx.x;
    __shared__ float fs_sh[DF];
    __shared__ float lds[4];
    fs_sh[j] = fs[i * DF + j];
    __syncthreads();
    const float4* fm4 = reinterpret_cast<const float4*>(fm + (size_t)j * DF);
    const float4* ef4 = reinterpret_cast<const float4*>(ef + (size_t)j * DF);
    const float4* fs4 = reinterpret_cast<const float4*>(fs_sh);
    float acc = 0.0f;
#pragma unroll 8
    for (int k = 0; k < DF / 4; ++k) {
        float4 m4 = fm4[k], e4 = ef4[k], s4 = fs4[k];
        float t0 = (s4.x - m4.x) * e4.x;
        float t1 = (s4.y - m4.y) * e4.y;
        float t2 = (s4.z - m4.z) * e4.z;
        float t3 = (s4.w - m4.w) * e4.w;
        acc += t0 * t0 + t1 * t1 + t2 * t2 + t3 * t3;
    }
    float val = -0.5f * (acc + wcf[j]);
    sum_f[i * B + j] = val;
    float m = blockReduceMax256(val, lds);
    float ssum = blockReduceSum256(expf(val - m), lds);
    if (j == 0) {
        float logq = m + logf(ssum) - LOG_C;
        hneg_f[i] = fmaxf(-logq, 0.0f);
    }
}

// sum_z[s,i,j] (+sum_f) + two logsumexps over j. grid=(B,STEP) (i,s), block=B (j).
__global__ void k_z(const float* __restrict__ zm_t, const float* __restrict__ e_t,
                    const float* __restrict__ zs_t, const float* __restrict__ wc,
                    const float* __restrict__ sum_f,
                    float* __restrict__ hneg_z, float* __restrict__ hneg_fz) {
    int i = blockIdx.x, s = blockIdx.y, j = threadIdx.x;
    __shared__ float zs_sh[DZ];
    __shared__ float lds[4];
    if (j < DZ) zs_sh[j] = zs_t[(s * B + i) * DZ + j];
    __syncthreads();
    const float4* zm4 = reinterpret_cast<const float4*>(zm_t + (size_t)(s * B + j) * DZ);
    const float4* e4p = reinterpret_cast<const float4*>(e_t + (size_t)(s * B + j) * DZ);
    const float4* zs4 = reinterpret_cast<const float4*>(zs_sh);
    float acc = 0.0f;
#pragma unroll
    for (int k = 0; k < DZ / 4; ++k) {
        float4 m4 = zm4[k], eV = e4p[k], sv = zs4[k];
        float t0 = (sv.x - m4.x) * eV.x;
        float t1 = (sv.y - m4.y) * eV.y;
        float t2 = (sv.z - m4.z) * eV.z;
        float t3 = (sv.w - m4.w) * eV.w;
        acc += t0 * t0 + t1 * t1 + t2 * t2 + t3 * t3;
    }
    float sz  = -0.5f * (acc + wc[s * B + j]);
    float szf = sz + sum_f[i * B + j];
    float m1 = blockReduceMax256(sz, lds);
    float e1 = blockReduceSum256(expf(sz - m1), lds);
    float m2 = blockReduceMax256(szf, lds);
    float e2 = blockReduceSum256(expf(szf - m2), lds);
    if (j == 0) {
        float lq_z  = m1 + logf(e1) - LOG_C;
        float lq_fz = m2 + logf(e2) - LOG_C;
        hneg_z[s * B + i]  = fmaxf(-lq_z, 0.0f);
        hneg_fz[s * B + i] = fmaxf(-lq_fz, 0.0f);
    }
}

// Final deterministic reduction -> scalar.
__global__ void k_final(const float* __restrict__ hneg_f, const float* __restrict__ hneg_z,
                        const float* __restrict__ hneg_fz, float* __restrict__ out) {
    __shared__ float lds[4];
    int t = threadIdx.x;
    float sf = hneg_f[t];
    float szv = 0.0f, sfz = 0.0f;
    for (int k = t; k < STEP * B; k += 256) {
        szv += hneg_z[k];
        sfz += hneg_fz[k];
    }
    float Hf  = blockReduceSum256(sf, lds) * (1.0f / B);
    float Hz  = blockReduceSum256(szv, lds) * (1.0f / (STEP * B));
    float Hfz = blockReduceSum256(sfz, lds) * (1.0f / (STEP * B));
    if (t == 0) out[0] = Hf + Hz - Hfz;
}

extern "C" void kernel_launch(void* const* d_in, const int* in_sizes, int n_in,
                              void* d_out, int out_size, void* d_ws, size_t ws_size,
                              hipStream_t stream) {
    const float* f_mean   = (const float*)d_in[0];
    const float* f_logvar = (const float*)d_in[1];
    const float* f_sample = (const float*)d_in[2];
    const float* z_mean   = (const float*)d_in[3];
    const float* z_logvar = (const float*)d_in[4];
    const float* z_sample = (const float*)d_in[5];
    float* out = (float*)d_out;

    float* w = (float*)d_ws;
    float* zm_t   = w;              w += STEP * B * DZ;   // 524288
    float* e_t    = w;              w += STEP * B * DZ;
    float* zs_t   = w;              w += STEP * B * DZ;
    float* wc     = w;              w += STEP * B;        // 8192
    float* ef     = w;              w += B * DF;          // 65536
    float* wcf    = w;              w += B;               // 256
    float* sum_f  = w;              w += B * B;           // 65536
    float* hneg_f = w;              w += B;               // 256
    float* hneg_z = w;              w += STEP * B;        // 8192
    float* hneg_fz= w;              w += STEP * B;        // 8192

    k_pre_z<<<dim3(B * STEP), dim3(DZ), 0, stream>>>(z_mean, z_logvar, z_sample,
                                                     zm_t, e_t, zs_t, wc);
    k_pre_f<<<dim3(B), dim3(DF), 0, stream>>>(f_logvar, ef, wcf);
    k_f<<<dim3(B), dim3(B), 0, stream>>>(f_mean, f_sample, ef, wcf, sum_f, hneg_f);
    k_z<<<dim3(B, STEP), dim3(B), 0, stream>>>(zm_t, e_t, zs_t, wc, sum_f,
                                               hneg_z, hneg_fz);
    k_final<<<dim3(1), dim3(256), 0, stream>>>(hneg_f, hneg_z, hneg_fz, out);
}

// Round 2
// 67.235 us; speedup vs baseline: 3.0653x; 3.0653x over previous
//
#include <hip/hip_runtime.h>
#include <math.h>

constexpr int B = 256, STEP = 32, DF = 256, DZ = 64;
constexpr int TI = 8;   // i-tile per k_z block
#define LOG_2PI 1.837877066409345f
#define LOG_C   16.36495572888985f   // log(256 * 50000)

__device__ __forceinline__ float warpReduceSum64(float v) {
    for (int o = 32; o > 0; o >>= 1) v += __shfl_down(v, o, 64);
    return v;
}

// 256-thread block reductions; lds must be float[4]; result valid in ALL threads.
__device__ __forceinline__ float blockReduceSum256(float v, float* lds) {
    int wid = threadIdx.x >> 6, lane = threadIdx.x & 63;
    v = warpReduceSum64(v);
    if (lane == 0) lds[wid] = v;
    __syncthreads();
    float r = lds[0] + lds[1] + lds[2] + lds[3];
    __syncthreads();
    return r;
}
__device__ __forceinline__ float blockReduceMax256(float v, float* lds) {
    int wid = threadIdx.x >> 6, lane = threadIdx.x & 63;
    for (int o = 32; o > 0; o >>= 1) v = fmaxf(v, __shfl_down(v, o, 64));
    if (lane == 0) lds[wid] = v;
    __syncthreads();
    float r = fmaxf(fmaxf(lds[0], lds[1]), fmaxf(lds[2], lds[3]));
    __syncthreads();
    return r;
}

// Transpose z arrays [B,STEP,DZ] -> [STEP,B,DZ]; precompute e=exp(-lv), wc[s,j]=sum_d(2lv+log2pi).
// grid = B*STEP blocks (b = j*STEP + s), block = 64 threads (d).
__global__ void k_pre_z(const float* __restrict__ zm, const float* __restrict__ zl,
                        const float* __restrict__ zs,
                        float* __restrict__ zm_t, float* __restrict__ e_t,
                        float* __restrict__ zs_t, float* __restrict__ wc) {
    int b = blockIdx.x;
    int d = threadIdx.x;
    int j = b / STEP, s = b % STEP;
    int src = b * DZ + d;
    int dst = (s * B + j) * DZ + d;
    float lv = zl[src];
    zm_t[dst] = zm[src];
    e_t[dst]  = expf(-lv);
    zs_t[dst] = zs[src];
    float r = warpReduceSum64(2.0f * lv + LOG_2PI);
    if (d == 0) wc[s * B + j] = r;
}

// Precompute ef[j,d]=exp(-f_logvar), wcf[j]=sum_d(2lv+log2pi). grid=B, block=DF.
__global__ void k_pre_f(const float* __restrict__ fl,
                        float* __restrict__ ef, float* __restrict__ wcf) {
    __shared__ float lds[4];
    int j = blockIdx.x, d = threadIdx.x;
    float lv = fl[j * DF + d];
    ef[j * DF + d] = expf(-lv);
    float r = blockReduceSum256(2.0f * lv + LOG_2PI, lds);
    if (d == 0) wcf[j] = r;
}

// sum_f[i,j] + logsumexp over j -> hneg_f[i]. grid=B (i), block=B (j).
__global__ void k_f(const float* __restrict__ fm, const float* __restrict__ fs,
                    const float* __restrict__ ef, const float* __restrict__ wcf,
                    float* __restrict__ sum_f, float* __restrict__ hneg_f) {
    int i = blockIdx.x, j = threadIdx.x;
    __shared__ float fs_sh[DF];
    __shared__ float lds[4];
    fs_sh[j] = fs[i * DF + j];
    __syncthreads();
    const float4* fm4 = reinterpret_cast<const float4*>(fm + (size_t)j * DF);
    const float4* ef4 = reinterpret_cast<const float4*>(ef + (size_t)j * DF);
    const float4* fs4 = reinterpret_cast<const float4*>(fs_sh);
    float acc = 0.0f;
#pragma unroll 8
    for (int k = 0; k < DF / 4; ++k) {
        float4 m4 = fm4[k], e4 = ef4[k], s4 = fs4[k];
        float t0 = (s4.x - m4.x) * e4.x;
        float t1 = (s4.y - m4.y) * e4.y;
        float t2 = (s4.z - m4.z) * e4.z;
        float t3 = (s4.w - m4.w) * e4.w;
        acc += t0 * t0 + t1 * t1 + t2 * t2 + t3 * t3;
    }
    float val = -0.5f * (acc + wcf[j]);
    sum_f[i * B + j] = val;
    float m = blockReduceMax256(val, lds);
    float ssum = blockReduceSum256(expf(val - m), lds);
    if (j == 0) {
        float logq = m + logf(ssum) - LOG_C;
        hneg_f[i] = fmaxf(-logq, 0.0f);
    }
}

// sum_z for a TI-tile of i's per block, with wave-parallel LSE reductions.
// grid=(B/TI, STEP) (i-tile, s), block=B (j).
__global__ void k_z(const float* __restrict__ zm_t, const float* __restrict__ e_t,
                    const float* __restrict__ zs_t, const float* __restrict__ wc,
                    const float* __restrict__ sum_f,
                    float* __restrict__ hneg_z, float* __restrict__ hneg_fz) {
    int it = blockIdx.x, s = blockIdx.y, j = threadIdx.x;
    int i0 = it * TI;
    __shared__ float zs_sh[TI][DZ];     // 2 KB
    __shared__ float red[2][TI][B];     // 16 KB

    // Stage TI sample rows: 128 float4 loads by the first 128 threads.
    if (j < TI * DZ / 4) {
        int i = j >> 4, c = j & 15;
        float4 v = *reinterpret_cast<const float4*>(
            &zs_t[(size_t)((s * B + i0 + i)) * DZ + c * 4]);
        *reinterpret_cast<float4*>(&zs_sh[i][c * 4]) = v;
    }
    __syncthreads();

    const float4* zm4 = reinterpret_cast<const float4*>(zm_t + (size_t)(s * B + j) * DZ);
    const float4* e4p = reinterpret_cast<const float4*>(e_t + (size_t)(s * B + j) * DZ);
    float acc[TI];
#pragma unroll
    for (int i = 0; i < TI; ++i) acc[i] = 0.0f;
#pragma unroll
    for (int k = 0; k < DZ / 4; ++k) {
        float4 m4 = zm4[k], eV = e4p[k];
        // precompute m*e once per chunk; then t = s*e - me (1 fma) per element
        float me0 = m4.x * eV.x, me1 = m4.y * eV.y, me2 = m4.z * eV.z, me3 = m4.w * eV.w;
#pragma unroll
        for (int i = 0; i < TI; ++i) {
            float4 sv = *reinterpret_cast<const float4*>(&zs_sh[i][k * 4]);
            float t0 = fmaf(sv.x, eV.x, -me0);
            float t1 = fmaf(sv.y, eV.y, -me1);
            float t2 = fmaf(sv.z, eV.z, -me2);
            float t3 = fmaf(sv.w, eV.w, -me3);
            acc[i] = fmaf(t0, t0, acc[i]);
            acc[i] = fmaf(t1, t1, acc[i]);
            acc[i] = fmaf(t2, t2, acc[i]);
            acc[i] = fmaf(t3, t3, acc[i]);
        }
    }
    float wcj = wc[s * B + j];
#pragma unroll
    for (int i = 0; i < TI; ++i) {
        float sz = -0.5f * (acc[i] + wcj);
        red[0][i][j] = sz;
        red[1][i][j] = sz + sum_f[(size_t)(i0 + i) * B + j];
    }
    __syncthreads();

    // 16 LSE tasks (TI i's x {z, fz}); wave w handles tasks 4w..4w+3.
    int wave = j >> 6, lane = j & 63;
#pragma unroll
    for (int t = 0; t < 4; ++t) {
        int task = wave * 4 + t;
        int type = task & 1, i = task >> 1;
        float v0 = red[type][i][lane];
        float v1 = red[type][i][lane + 64];
        float v2 = red[type][i][lane + 128];
        float v3 = red[type][i][lane + 192];
        float m = fmaxf(fmaxf(v0, v1), fmaxf(v2, v3));
        for (int o = 32; o > 0; o >>= 1) m = fmaxf(m, __shfl_xor(m, o, 64));
        float ssum = expf(v0 - m) + expf(v1 - m) + expf(v2 - m) + expf(v3 - m);
        for (int o = 32; o > 0; o >>= 1) ssum += __shfl_xor(ssum, o, 64);
        if (lane == 0) {
            float lq = m + logf(ssum) - LOG_C;
            float h = fmaxf(-lq, 0.0f);
            if (type == 0) hneg_z[s * B + i0 + i] = h;
            else           hneg_fz[s * B + i0 + i] = h;
        }
    }
}

// Final deterministic reduction -> scalar.
__global__ void k_final(const float* __restrict__ hneg_f, const float* __restrict__ hneg_z,
                        const float* __restrict__ hneg_fz, float* __restrict__ out) {
    __shared__ float lds[4];
    int t = threadIdx.x;
    float sf = hneg_f[t];
    float szv = 0.0f, sfz = 0.0f;
    for (int k = t; k < STEP * B; k += 256) {
        szv += hneg_z[k];
        sfz += hneg_fz[k];
    }
    float Hf  = blockReduceSum256(sf, lds) * (1.0f / B);
    float Hz  = blockReduceSum256(szv, lds) * (1.0f / (STEP * B));
    float Hfz = blockReduceSum256(sfz, lds) * (1.0f / (STEP * B));
    if (t == 0) out[0] = Hf + Hz - Hfz;
}

extern "C" void kernel_launch(void* const* d_in, const int* in_sizes, int n_in,
                              void* d_out, int out_size, void* d_ws, size_t ws_size,
                              hipStream_t stream) {
    const float* f_mean   = (const float*)d_in[0];
    const float* f_logvar = (const float*)d_in[1];
    const float* f_sample = (const float*)d_in[2];
    const float* z_mean   = (const float*)d_in[3];
    const float* z_logvar = (const float*)d_in[4];
    const float* z_sample = (const float*)d_in[5];
    float* out = (float*)d_out;

    float* w = (float*)d_ws;
    float* zm_t   = w;              w += STEP * B * DZ;   // 524288
    float* e_t    = w;              w += STEP * B * DZ;
    float* zs_t   = w;              w += STEP * B * DZ;
    float* wc     = w;              w += STEP * B;        // 8192
    float* ef     = w;              w += B * DF;          // 65536
    float* wcf    = w;              w += B;               // 256
    float* sum_f  = w;              w += B * B;           // 65536
    float* hneg_f = w;              w += B;               // 256
    float* hneg_z = w;              w += STEP * B;        // 8192
    float* hneg_fz= w;              w += STEP * B;        // 8192

    k_pre_z<<<dim3(B * STEP), dim3(DZ), 0, stream>>>(z_mean, z_logvar, z_sample,
                                                     zm_t, e_t, zs_t, wc);
    k_pre_f<<<dim3(B), dim3(DF), 0, stream>>>(f_logvar, ef, wcf);
    k_f<<<dim3(B), dim3(B), 0, stream>>>(f_mean, f_sample, ef, wcf, sum_f, hneg_f);
    k_z<<<dim3(B / TI, STEP), dim3(B), 0, stream>>>(zm_t, e_t, zs_t, wc, sum_f,
                                                    hneg_z, hneg_fz);
    k_final<<<dim3(1), dim3(256), 0, stream>>>(hneg_f, hneg_z, hneg_fz, out);
}